// Round 1
// baseline (1467.615 us; speedup 1.0000x reference)
//
#include <hip/hip_runtime.h>
#include <hip/hip_bf16.h>
#include <math.h>

// NeuralMemory: fused projections -> 2-layer residual MLP fwd -> grads (Ws,bs)
// -> AdamW(step1) -> retrieved with new weights. fp32 baseline, tiled GEMMs.
//
// Shapes: N=32768 tokens, D=256, L=2.
// Outputs: retrieved [N,256] | -gWs [2,256,256] | -gbs [2,256]  (fp32, concat)

#define NTOK 32768
#define DD 256
#define LRc 1e-3f
#define WDc 1e-2f
#define EPSc 1e-8f

__device__ __forceinline__ float sigm(float z) { return 1.f / (1.f + __expf(-z)); }
__device__ __forceinline__ float siluf(float z) { return z * sigm(z); }
__device__ __forceinline__ float dsiluf(float z) {
    float s = sigm(z);
    return s * (1.f + z * (1.f - s));
}

// ---------------------------------------------------------------------------
// Generic tiled GEMM: C[M,256] = A[M,256] @ B(256,256) (+epilogue)
// BM=128, BN=128, BK=16, 256 threads, 8x8 per thread.
// EPI 0: C = A@B
// EPI 1: Z = A@B + bias; C = A + silu(Z)        (lmm forward, saves Z)
// EPI 2: C = R + A@B                            (dh1 = dh2 + dz1@W1^T)
// EPI 3: C = A + silu(A@B + bias)               (retrieved layers, no Z)
// TRANSB: B indexed as B[n][k] (i.e. multiply by B^T)
// ---------------------------------------------------------------------------
template <int EPI, bool TRANSB>
__global__ __launch_bounds__(256) void gemm_k(const float* __restrict__ A,
                                              const float* __restrict__ B,
                                              const float* __restrict__ bias,
                                              const float* __restrict__ R,
                                              float* C, float* Z) {
    __shared__ float As[16][128];
    __shared__ float Bs[16][128];
    const int tid = threadIdx.x;
    const int n0 = blockIdx.x * 128;
    const int m0 = blockIdx.y * 128;
    const int tx = tid & 15, ty = tid >> 4;

    float acc[8][8];
#pragma unroll
    for (int i = 0; i < 8; i++)
#pragma unroll
        for (int j = 0; j < 8; j++) acc[i][j] = 0.f;

    for (int k0 = 0; k0 < DD; k0 += 16) {
        // Stage A tile (transposed into As[k][m])
#pragma unroll
        for (int q = 0; q < 2; q++) {
            int idx = q * 256 + tid;
            int r = idx >> 2, c4 = (idx & 3) << 2;
            float4 v = *(const float4*)(A + (size_t)(m0 + r) * DD + k0 + c4);
            As[c4 + 0][r] = v.x;
            As[c4 + 1][r] = v.y;
            As[c4 + 2][r] = v.z;
            As[c4 + 3][r] = v.w;
        }
        if (!TRANSB) {
#pragma unroll
            for (int q = 0; q < 2; q++) {
                int idx = q * 256 + tid;
                int c = idx >> 5, j4 = (idx & 31) << 2;
                *(float4*)&Bs[c][j4] =
                    *(const float4*)(B + (size_t)(k0 + c) * DD + n0 + j4);
            }
        } else {
#pragma unroll
            for (int q = 0; q < 2; q++) {
                int idx = q * 256 + tid;
                int j = idx >> 2, c4 = (idx & 3) << 2;
                float4 v = *(const float4*)(B + (size_t)(n0 + j) * DD + k0 + c4);
                Bs[c4 + 0][j] = v.x;
                Bs[c4 + 1][j] = v.y;
                Bs[c4 + 2][j] = v.z;
                Bs[c4 + 3][j] = v.w;
            }
        }
        __syncthreads();
#pragma unroll
        for (int kk = 0; kk < 16; kk++) {
            float a[8], b[8];
            *(float4*)&a[0] = *(const float4*)&As[kk][ty * 8];
            *(float4*)&a[4] = *(const float4*)&As[kk][ty * 8 + 4];
            *(float4*)&b[0] = *(const float4*)&Bs[kk][tx * 8];
            *(float4*)&b[4] = *(const float4*)&Bs[kk][tx * 8 + 4];
#pragma unroll
            for (int i = 0; i < 8; i++)
#pragma unroll
                for (int j = 0; j < 8; j++)
                    acc[i][j] = fmaf(a[i], b[j], acc[i][j]);
        }
        __syncthreads();
    }

    const int crow = m0 + ty * 8;
    const int ccol = n0 + tx * 8;
    float bi[8];
    if (EPI == 1 || EPI == 3) {
#pragma unroll
        for (int j = 0; j < 8; j++) bi[j] = bias[ccol + j];
    }
#pragma unroll
    for (int i = 0; i < 8; i++) {
        size_t base = (size_t)(crow + i) * DD + ccol;
        float outv[8];
        if (EPI == 0) {
#pragma unroll
            for (int j = 0; j < 8; j++) outv[j] = acc[i][j];
        } else if (EPI == 2) {
            float4 r0 = *(const float4*)(R + base);
            float4 r1 = *(const float4*)(R + base + 4);
            float rv[8] = {r0.x, r0.y, r0.z, r0.w, r1.x, r1.y, r1.z, r1.w};
#pragma unroll
            for (int j = 0; j < 8; j++) outv[j] = rv[j] + acc[i][j];
        } else {  // EPI 1 or 3: residual + silu
            float4 a0 = *(const float4*)(A + base);
            float4 a1 = *(const float4*)(A + base + 4);
            float av[8] = {a0.x, a0.y, a0.z, a0.w, a1.x, a1.y, a1.z, a1.w};
            float zv[8];
#pragma unroll
            for (int j = 0; j < 8; j++) {
                zv[j] = acc[i][j] + bi[j];
                outv[j] = av[j] + siluf(zv[j]);
            }
            if (EPI == 1) {
                *(float4*)(Z + base) = make_float4(zv[0], zv[1], zv[2], zv[3]);
                *(float4*)(Z + base + 4) = make_float4(zv[4], zv[5], zv[6], zv[7]);
            }
        }
        *(float4*)(C + base) = make_float4(outv[0], outv[1], outv[2], outv[3]);
        *(float4*)(C + base + 4) = make_float4(outv[4], outv[5], outv[6], outv[7]);
    }
}

// ---------------------------------------------------------------------------
// Reduction GEMM: gW[i][j] += sum_t A[t][i]*Dz[t][j], split-K over token
// chunks of 512, atomicAdd epilogue. Grid (2,2,64), 256 threads, 8x8/thread.
// ---------------------------------------------------------------------------
__global__ __launch_bounds__(256) void redgemm_k(const float* __restrict__ A,
                                                 const float* __restrict__ Dz,
                                                 float* gW) {
    __shared__ float As[16][128];
    __shared__ float Ds[16][128];
    const int tid = threadIdx.x;
    const int i0 = blockIdx.x * 128, j0 = blockIdx.y * 128;
    const int t0 = blockIdx.z * 512;
    const int tx = tid & 15, ty = tid >> 4;

    float acc[8][8];
#pragma unroll
    for (int i = 0; i < 8; i++)
#pragma unroll
        for (int j = 0; j < 8; j++) acc[i][j] = 0.f;

    for (int tb = t0; tb < t0 + 512; tb += 16) {
#pragma unroll
        for (int q = 0; q < 2; q++) {
            int idx = q * 256 + tid;
            int c = idx >> 5, i4 = (idx & 31) << 2;
            *(float4*)&As[c][i4] =
                *(const float4*)(A + (size_t)(tb + c) * DD + i0 + i4);
            *(float4*)&Ds[c][i4] =
                *(const float4*)(Dz + (size_t)(tb + c) * DD + j0 + i4);
        }
        __syncthreads();
#pragma unroll
        for (int c = 0; c < 16; c++) {
            float a[8], d[8];
            *(float4*)&a[0] = *(const float4*)&As[c][ty * 8];
            *(float4*)&a[4] = *(const float4*)&As[c][ty * 8 + 4];
            *(float4*)&d[0] = *(const float4*)&Ds[c][tx * 8];
            *(float4*)&d[4] = *(const float4*)&Ds[c][tx * 8 + 4];
#pragma unroll
            for (int i = 0; i < 8; i++)
#pragma unroll
                for (int j = 0; j < 8; j++)
                    acc[i][j] = fmaf(a[i], d[j], acc[i][j]);
        }
        __syncthreads();
    }
#pragma unroll
    for (int i = 0; i < 8; i++)
#pragma unroll
        for (int j = 0; j < 8; j++)
            atomicAdd(&gW[(size_t)(i0 + ty * 8 + i) * DD + j0 + tx * 8 + j],
                      acc[i][j]);
}

// ---------------------------------------------------------------------------
// alr = sigmoid(x @ Wlr + blr) * 0.1 ; one wave per token
// ---------------------------------------------------------------------------
__global__ __launch_bounds__(256) void alr_k(const float* __restrict__ x,
                                             const float* __restrict__ Wlr,
                                             const float* __restrict__ blr,
                                             float* __restrict__ alr) {
    const int wave = threadIdx.x >> 6, lane = threadIdx.x & 63;
    const int t = blockIdx.x * 4 + wave;
    const float* xr = x + (size_t)t * DD;
    float s = 0.f;
#pragma unroll
    for (int i = 0; i < 4; i++) s += xr[lane + i * 64] * Wlr[lane + i * 64];
#pragma unroll
    for (int off = 32; off; off >>= 1) s += __shfl_down(s, off);
    if (lane == 0) {
        alr[t] = 0.1f * sigm(s + blr[0]);
    }
}

// ---------------------------------------------------------------------------
// dh2 = (2/D)*alr*(h2 - V);  dz1 = dh2 * silu'(z1);  gb1 += colsum(dz1)
// In-place: dz1 -> V's buffer, dh2 -> z1's buffer (same-index, no restrict).
// ---------------------------------------------------------------------------
__global__ __launch_bounds__(256) void dzdh_k(const float* h2, const float* V,
                                              const float* z1,
                                              const float* __restrict__ alr,
                                              float* dz1o, float* dh2o,
                                              float* gb) {
    const int tid = threadIdx.x;
    const int colq = tid & 63;   // float4 column index (cols colq*4 .. +3)
    const int rof = tid >> 6;
    float g0 = 0, g1 = 0, g2 = 0, g3 = 0;
    for (int r = blockIdx.x * 4 + rof; r < NTOK; r += gridDim.x * 4) {
        size_t q = (size_t)r * 64 + colq;
        float4 h = ((const float4*)h2)[q];
        float4 v = ((const float4*)V)[q];
        float4 z = ((const float4*)z1)[q];
        float a = alr[r] * (2.f / 256.f);
        float4 dh, dz;
        dh.x = a * (h.x - v.x);
        dh.y = a * (h.y - v.y);
        dh.z = a * (h.z - v.z);
        dh.w = a * (h.w - v.w);
        dz.x = dh.x * dsiluf(z.x);
        dz.y = dh.y * dsiluf(z.y);
        dz.z = dh.z * dsiluf(z.z);
        dz.w = dh.w * dsiluf(z.w);
        ((float4*)dz1o)[q] = dz;
        ((float4*)dh2o)[q] = dh;
        g0 += dz.x;
        g1 += dz.y;
        g2 += dz.z;
        g3 += dz.w;
    }
    atomicAdd(&gb[colq * 4 + 0], g0);
    atomicAdd(&gb[colq * 4 + 1], g1);
    atomicAdd(&gb[colq * 4 + 2], g2);
    atomicAdd(&gb[colq * 4 + 3], g3);
}

// dz0 = dh1 * silu'(z0) (in-place into dh1's buffer); gb0 += colsum(dz0)
__global__ __launch_bounds__(256) void dz0_k(const float* dh1, const float* z0,
                                             float* dz0o, float* gb) {
    const int tid = threadIdx.x;
    const int colq = tid & 63;
    const int rof = tid >> 6;
    float g0 = 0, g1 = 0, g2 = 0, g3 = 0;
    for (int r = blockIdx.x * 4 + rof; r < NTOK; r += gridDim.x * 4) {
        size_t q = (size_t)r * 64 + colq;
        float4 d = ((const float4*)dh1)[q];
        float4 z = ((const float4*)z0)[q];
        float4 dz;
        dz.x = d.x * dsiluf(z.x);
        dz.y = d.y * dsiluf(z.y);
        dz.z = d.z * dsiluf(z.z);
        dz.w = d.w * dsiluf(z.w);
        ((float4*)dz0o)[q] = dz;
        g0 += dz.x;
        g1 += dz.y;
        g2 += dz.z;
        g3 += dz.w;
    }
    atomicAdd(&gb[colq * 4 + 0], g0);
    atomicAdd(&gb[colq * 4 + 1], g1);
    atomicAdd(&gb[colq * 4 + 2], g2);
    atomicAdd(&gb[colq * 4 + 3], g3);
}

// AdamW step-1 from zero state + surprises output
__global__ __launch_bounds__(256) void adamw_k(
    const float* __restrict__ Ws, const float* __restrict__ bs,
    const float* __restrict__ accW, const float* __restrict__ accB,
    float* __restrict__ nW, float* __restrict__ nb, float* __restrict__ outSW,
    float* __restrict__ outSb) {
    int i = blockIdx.x * 256 + threadIdx.x;
    if (i < 2 * DD * DD) {
        float g = accW[i];
        outSW[i] = -g;
        nW[i] = Ws[i] * (1.f - LRc * WDc) - LRc * g / (fabsf(g) + EPSc);
    }
    if (i < 2 * DD) {
        float g = accB[i];
        outSb[i] = -g;
        nb[i] = bs[i] * (1.f - LRc * WDc) - LRc * g / (fabsf(g) + EPSc);
    }
}

__global__ void zero_k(float* p, int n) {
    int i = blockIdx.x * 256 + threadIdx.x;
    if (i < n) p[i] = 0.f;
}

extern "C" void kernel_launch(void* const* d_in, const int* in_sizes, int n_in,
                              void* d_out, int out_size, void* d_ws,
                              size_t ws_size, hipStream_t stream) {
    const float* x = (const float*)d_in[0];
    const float* Wk = (const float*)d_in[1];
    const float* Wq = (const float*)d_in[2];
    const float* Wv = (const float*)d_in[3];
    const float* Wlr = (const float*)d_in[4];
    const float* blr = (const float*)d_in[5];
    const float* Ws = (const float*)d_in[6];
    const float* bs = (const float*)d_in[7];

    float* ws = (float*)d_ws;
    const size_t NM = (size_t)NTOK * DD;  // 8388608
    float* K = ws + 0 * NM;               // keys, later r1
    float* Q = ws + 1 * NM;
    float* V = ws + 2 * NM;   // values, later dz1
    float* z0 = ws + 3 * NM;
    float* h1 = ws + 4 * NM;
    float* z1 = ws + 5 * NM;  // later dh2
    float* h2 = ws + 6 * NM;  // later dh1, then dz0
    float* alr = ws + 7 * NM;
    float* accW = alr + NTOK;       // [2*256*256]
    float* accB = accW + 2 * DD * DD;  // [512]
    float* nW = accB + 2 * DD;
    float* nb = nW + 2 * DD * DD;

    float* out_ret = (float*)d_out;
    float* out_sW = out_ret + NM;
    float* out_sb = out_sW + 2 * DD * DD;

    dim3 blk(256);
    dim3 g_gemm(2, NTOK / 128);
    dim3 g_red(2, 2, 64);

    // zero grad accumulators (ws is poisoned each call)
    zero_k<<<dim3((2 * DD * DD + 2 * DD + 255) / 256), blk, 0, stream>>>(
        accW, 2 * DD * DD + 2 * DD);

    // projections
    gemm_k<0, false><<<g_gemm, blk, 0, stream>>>(x, Wk, nullptr, nullptr, K, nullptr);
    gemm_k<0, false><<<g_gemm, blk, 0, stream>>>(x, Wq, nullptr, nullptr, Q, nullptr);
    gemm_k<0, false><<<g_gemm, blk, 0, stream>>>(x, Wv, nullptr, nullptr, V, nullptr);
    alr_k<<<dim3(NTOK / 4), blk, 0, stream>>>(x, Wlr, blr, alr);

    // lmm forward (save z0, z1)
    gemm_k<1, false><<<g_gemm, blk, 0, stream>>>(K, Ws, bs, nullptr, h1, z0);
    gemm_k<1, false><<<g_gemm, blk, 0, stream>>>(h1, Ws + DD * DD, bs + DD,
                                                 nullptr, h2, z1);

    // backward
    dzdh_k<<<dim3(256), blk, 0, stream>>>(h2, V, z1, alr, /*dz1*/ V,
                                          /*dh2*/ z1, accB + DD);
    redgemm_k<<<g_red, blk, 0, stream>>>(h1, /*dz1*/ V, accW + DD * DD);
    gemm_k<2, true><<<g_gemm, blk, 0, stream>>>(/*dz1*/ V, Ws + DD * DD,
                                                nullptr, /*dh2*/ z1,
                                                /*dh1*/ h2, nullptr);
    dz0_k<<<dim3(256), blk, 0, stream>>>(/*dh1*/ h2, z0, /*dz0*/ h2, accB);
    redgemm_k<<<g_red, blk, 0, stream>>>(K, /*dz0*/ h2, accW);

    // AdamW + surprises
    adamw_k<<<dim3(512), blk, 0, stream>>>(Ws, bs, accW, accB, nW, nb, out_sW,
                                           out_sb);

    // retrieved with new weights (reuse K as r1)
    gemm_k<3, false><<<g_gemm, blk, 0, stream>>>(Q, nW, nb, nullptr, /*r1*/ K,
                                                 nullptr);
    gemm_k<3, false><<<g_gemm, blk, 0, stream>>>(/*r1*/ K, nW + DD * DD,
                                                 nb + DD, nullptr, out_ret,
                                                 nullptr);
}

// Round 2
// 409.427 us; speedup vs baseline: 3.5846x; 3.5846x over previous
//
#include <hip/hip_runtime.h>
#include <math.h>

// NeuralMemory on MI355X — bf16 MFMA rewrite.
// All GEMMs: mfma_f32_16x16x32_bf16, 128x128 tile, BK=32, global_load_lds(16B).
// Reduction GEMMs via explicit bf16 transposes + split-K partials.
// N=32768 tokens, D=256.

#define NTOK 32768
#define NM ((size_t)NTOK * 256)
#define LRc 1e-3f
#define WDc 1e-2f
#define EPSc 1e-8f

typedef __attribute__((ext_vector_type(8))) short bf16x8;
typedef __attribute__((ext_vector_type(4))) float f32x4;

__device__ __forceinline__ float b2f(unsigned short u) {
    union { unsigned int i; float f; } c;
    c.i = ((unsigned int)u) << 16;
    return c.f;
}
__device__ __forceinline__ unsigned short f2b(float f) {
    union { float f; unsigned int i; } c;
    c.f = f;
    unsigned int i = c.i;
    return (unsigned short)((i + 0x7FFFu + ((i >> 16) & 1u)) >> 16);
}
__device__ __forceinline__ float sigm(float z) { return 1.f / (1.f + __expf(-z)); }
__device__ __forceinline__ float siluf(float z) { return z * sigm(z); }
__device__ __forceinline__ float dsiluf(float z) {
    float s = sigm(z);
    return s * (1.f + z * (1.f - s));
}

__device__ __forceinline__ void gl16(const void* g, void* l) {
    __builtin_amdgcn_global_load_lds(
        (const __attribute__((address_space(1))) void*)g,
        (__attribute__((address_space(3))) void*)l, 16, 0, 0);
}

// ---------------------------------------------------------------------------
// Tall MFMA GEMM: C[M,256] = A[M,256] @ B, B given pre-transposed bf16
// (Bt[n][k] = B[k][n]). 128x128 tile, 4 waves (2x2 of 64x64), BK=32.
// EPI 0: Cb = A@B (bf16), batched over blockIdx.z (proj K/Q/V)
// EPI 1: z = acc+bias; Zout=z; Cb = A + silu(z)        (lmm forward)
// EPI 2: dh1 = acc + R; Cb = dh1 * dsilu(Zin)          (backward fused)
// EPI 3: Cb = A + silu(acc+bias)                       (retrieved L0)
// EPI 4: Cf = A + silu(acc+bias)  (fp32 final output)  (retrieved L1)
// ---------------------------------------------------------------------------
template <int EPI>
__global__ __launch_bounds__(256) void mgemm_k(
    const unsigned short* __restrict__ A, const unsigned short* __restrict__ Bt,
    const float* __restrict__ bias, const unsigned short* __restrict__ R,
    const unsigned short* __restrict__ Zin, unsigned short* __restrict__ Cb,
    float* __restrict__ Cf, unsigned short* __restrict__ Zout, size_t zcs) {
    __shared__ short As[4096];
    __shared__ short Bs[4096];
    Bt += (size_t)blockIdx.z * 65536;
    const size_t coff = (size_t)blockIdx.z * zcs;
    const int n0 = blockIdx.x * 128, m0 = blockIdx.y * 128;
    const int tid = threadIdx.x, lane = tid & 63, wave = tid >> 6;
    const int wr = (wave >> 1) * 64, wc = (wave & 1) * 64;
    const int fr = lane & 15, fk = (lane >> 4) * 8;
    const int sr = lane >> 2, sc = (lane & 3) * 8;

    f32x4 acc[4][4];
#pragma unroll
    for (int i = 0; i < 4; i++)
#pragma unroll
        for (int j = 0; j < 4; j++) acc[i][j] = (f32x4){0.f, 0.f, 0.f, 0.f};

    for (int k0 = 0; k0 < 256; k0 += 32) {
#pragma unroll
        for (int t = 0; t < 2; t++) {
            const int slot = wave * 2 + t;
            const int r = slot * 16 + sr;
            gl16(&A[(size_t)(m0 + r) * 256 + k0 + sc], &As[slot * 512]);
            gl16(&Bt[(size_t)(n0 + r) * 256 + k0 + sc], &Bs[slot * 512]);
        }
        __syncthreads();
        bf16x8 af[4], bfr[4];
#pragma unroll
        for (int i = 0; i < 4; i++) {
            af[i] = *(const bf16x8*)&As[(wr + i * 16 + fr) * 32 + fk];
            bfr[i] = *(const bf16x8*)&Bs[(wc + i * 16 + fr) * 32 + fk];
        }
#pragma unroll
        for (int i = 0; i < 4; i++)
#pragma unroll
            for (int j = 0; j < 4; j++)
                acc[i][j] = __builtin_amdgcn_mfma_f32_16x16x32_bf16(
                    af[i], bfr[j], acc[i][j], 0, 0, 0);
        __syncthreads();
    }

    const int r0 = (lane >> 4) * 4, cc = lane & 15;
#pragma unroll
    for (int mi = 0; mi < 4; mi++)
#pragma unroll
        for (int ni = 0; ni < 4; ni++) {
            const int gcol = n0 + wc + ni * 16 + cc;
            float bv = 0.f;
            if (EPI == 1 || EPI == 3 || EPI == 4) bv = bias[gcol];
            f32x4 c = acc[mi][ni];
#pragma unroll
            for (int r = 0; r < 4; r++) {
                const int grow = m0 + wr + mi * 16 + r0 + r;
                const size_t off = (size_t)grow * 256 + gcol;
                const float v = c[r];
                if (EPI == 0) {
                    Cb[coff + off] = f2b(v);
                } else if (EPI == 1) {
                    float z = v + bv;
                    Zout[off] = f2b(z);
                    Cb[off] = f2b(b2f(A[off]) + siluf(z));
                } else if (EPI == 2) {
                    float dh1 = v + b2f(R[off]);
                    Cb[off] = f2b(dh1 * dsiluf(b2f(Zin[off])));
                } else if (EPI == 3) {
                    Cb[off] = f2b(b2f(A[off]) + siluf(v + bv));
                } else {
                    Cf[off] = b2f(A[off]) + siluf(v + bv);
                }
            }
        }
}

// ---------------------------------------------------------------------------
// Reduction GEMM: gW[l][i][j] = sum_t X[t][i] dz[t][j], via transposed bf16
// inputs XT[i][t], dzT[j][t]. Split-K: z in [0,128): layer=z>>6, chunk of 512.
// Writes fp32 partials pbuf[layer][chunk][i][j].
// ---------------------------------------------------------------------------
__global__ __launch_bounds__(256) void rgemm_k(
    const unsigned short* __restrict__ KT, const unsigned short* __restrict__ h1T,
    const unsigned short* __restrict__ dz0T,
    const unsigned short* __restrict__ dz1T, float* __restrict__ pbuf) {
    __shared__ short As[4096];
    __shared__ short Bs[4096];
    const int z = blockIdx.z, layer = z >> 6, zc = z & 63;
    const unsigned short* Ag = layer ? h1T : KT;
    const unsigned short* Bg = layer ? dz1T : dz0T;
    const int t0 = zc * 512;
    const int j0 = blockIdx.x * 128, i0 = blockIdx.y * 128;
    const int tid = threadIdx.x, lane = tid & 63, wave = tid >> 6;
    const int wr = (wave >> 1) * 64, wc = (wave & 1) * 64;
    const int fr = lane & 15, fk = (lane >> 4) * 8;
    const int sr = lane >> 2, sc = (lane & 3) * 8;

    f32x4 acc[4][4];
#pragma unroll
    for (int i = 0; i < 4; i++)
#pragma unroll
        for (int j = 0; j < 4; j++) acc[i][j] = (f32x4){0.f, 0.f, 0.f, 0.f};

    for (int tt = t0; tt < t0 + 512; tt += 32) {
#pragma unroll
        for (int t = 0; t < 2; t++) {
            const int slot = wave * 2 + t;
            const int r = slot * 16 + sr;
            gl16(&Ag[(size_t)(i0 + r) * 32768 + tt + sc], &As[slot * 512]);
            gl16(&Bg[(size_t)(j0 + r) * 32768 + tt + sc], &Bs[slot * 512]);
        }
        __syncthreads();
        bf16x8 af[4], bfr[4];
#pragma unroll
        for (int i = 0; i < 4; i++) {
            af[i] = *(const bf16x8*)&As[(wr + i * 16 + fr) * 32 + fk];
            bfr[i] = *(const bf16x8*)&Bs[(wc + i * 16 + fr) * 32 + fk];
        }
#pragma unroll
        for (int i = 0; i < 4; i++)
#pragma unroll
            for (int j = 0; j < 4; j++)
                acc[i][j] = __builtin_amdgcn_mfma_f32_16x16x32_bf16(
                    af[i], bfr[j], acc[i][j], 0, 0, 0);
        __syncthreads();
    }

    float* P = pbuf + (size_t)(layer * 64 + zc) * 65536;
    const int r0 = (lane >> 4) * 4, cc = lane & 15;
#pragma unroll
    for (int mi = 0; mi < 4; mi++)
#pragma unroll
        for (int ni = 0; ni < 4; ni++) {
            f32x4 c = acc[mi][ni];
#pragma unroll
            for (int r = 0; r < 4; r++)
                P[(size_t)(i0 + wr + mi * 16 + r0 + r) * 256 +
                  (j0 + wc + ni * 16 + cc)] = c[r];
        }
}

__global__ void reduce_k(const float* __restrict__ pbuf, float* __restrict__ accW) {
    int idx = blockIdx.x * 256 + threadIdx.x;  // 131072
    int layer = idx >> 16, rc = idx & 65535;
    const float* p = pbuf + (size_t)layer * 64 * 65536 + rc;
    float s = 0.f;
#pragma unroll 8
    for (int c = 0; c < 64; c++) s += p[(size_t)c * 65536];
    accW[idx] = s;
}

// bf16 [32768,256] -> [256,32768] transpose (3 pairs via blockIdx.z)
__global__ __launch_bounds__(256) void trans_k(
    const unsigned short* __restrict__ s0, const unsigned short* __restrict__ s1,
    const unsigned short* __restrict__ s2, unsigned short* __restrict__ d0,
    unsigned short* __restrict__ d1, unsigned short* __restrict__ d2) {
    const unsigned short* src = blockIdx.z == 0 ? s0 : blockIdx.z == 1 ? s1 : s2;
    unsigned short* dst = blockIdx.z == 0 ? d0 : blockIdx.z == 1 ? d1 : d2;
    __shared__ unsigned short ts[64 * 65];
    const int n0 = blockIdx.x * 64, c0 = blockIdx.y * 64;
    const int tid = threadIdx.x;
#pragma unroll
    for (int it = 0; it < 2; it++) {
        int idx = it * 256 + tid;
        int r = idx >> 3, c8 = (idx & 7) * 8;
        uint4 v = *(const uint4*)&src[(size_t)(n0 + r) * 256 + c0 + c8];
        unsigned short* p = &ts[r * 65 + c8];
        p[0] = (unsigned short)v.x; p[1] = (unsigned short)(v.x >> 16);
        p[2] = (unsigned short)v.y; p[3] = (unsigned short)(v.y >> 16);
        p[4] = (unsigned short)v.z; p[5] = (unsigned short)(v.z >> 16);
        p[6] = (unsigned short)v.w; p[7] = (unsigned short)(v.w >> 16);
    }
    __syncthreads();
#pragma unroll
    for (int it = 0; it < 2; it++) {
        int idx = it * 256 + tid;
        int d = idx >> 3, r8 = (idx & 7) * 8;
        unsigned int a0 = (unsigned int)ts[(r8 + 0) * 65 + d] |
                          ((unsigned int)ts[(r8 + 1) * 65 + d] << 16);
        unsigned int a1 = (unsigned int)ts[(r8 + 2) * 65 + d] |
                          ((unsigned int)ts[(r8 + 3) * 65 + d] << 16);
        unsigned int a2 = (unsigned int)ts[(r8 + 4) * 65 + d] |
                          ((unsigned int)ts[(r8 + 5) * 65 + d] << 16);
        unsigned int a3 = (unsigned int)ts[(r8 + 6) * 65 + d] |
                          ((unsigned int)ts[(r8 + 7) * 65 + d] << 16);
        uint4 o = make_uint4(a0, a1, a2, a3);
        *(uint4*)&dst[(size_t)(c0 + d) * 32768 + n0 + r8] = o;
    }
}

__global__ void cvtx_k(const float* __restrict__ x, unsigned short* __restrict__ xb) {
    size_t i = ((size_t)blockIdx.x * 256 + threadIdx.x) * 8;
    float4 a = *(const float4*)(x + i);
    float4 b = *(const float4*)(x + i + 4);
    unsigned int w0 = (unsigned int)f2b(a.x) | ((unsigned int)f2b(a.y) << 16);
    unsigned int w1 = (unsigned int)f2b(a.z) | ((unsigned int)f2b(a.w) << 16);
    unsigned int w2 = (unsigned int)f2b(b.x) | ((unsigned int)f2b(b.y) << 16);
    unsigned int w3 = (unsigned int)f2b(b.z) | ((unsigned int)f2b(b.w) << 16);
    *(uint4*)(xb + i) = make_uint4(w0, w1, w2, w3);
}

// weight prep: z=0..4 transpose+cvt {Wk,Wq,Wv,Ws0,Ws1}; z=5 straight cvt Ws1
__global__ void wprep_k(const float* __restrict__ Wk, const float* __restrict__ Wq,
                        const float* __restrict__ Wv, const float* __restrict__ Ws,
                        unsigned short* __restrict__ wt) {
    const int z = blockIdx.y;
    const int idx = blockIdx.x * 256 + threadIdx.x;  // 0..65535
    const float* src = z == 0 ? Wk : z == 1 ? Wq : z == 2 ? Wv
                     : z == 3 ? Ws : Ws + 65536;
    unsigned short* dst = wt + (size_t)z * 65536;
    float v = src[idx];
    if (z == 5)
        dst[idx] = f2b(v);
    else
        dst[(idx & 255) * 256 + (idx >> 8)] = f2b(v);
}

__global__ __launch_bounds__(256) void alr_k(const float* __restrict__ x,
                                             const float* __restrict__ Wlr,
                                             const float* __restrict__ blr,
                                             float* __restrict__ alr) {
    const int wave = threadIdx.x >> 6, lane = threadIdx.x & 63;
    const int t = blockIdx.x * 4 + wave;
    const float* xr = x + (size_t)t * 256;
    float s = 0.f;
#pragma unroll
    for (int i = 0; i < 4; i++) s += xr[lane + i * 64] * Wlr[lane + i * 64];
#pragma unroll
    for (int off = 32; off; off >>= 1) s += __shfl_down(s, off);
    if (lane == 0) alr[t] = 0.1f * sigm(s + blr[0]);
}

__global__ void dzdh_k(const unsigned short* __restrict__ h2b,
                       const unsigned short* __restrict__ Vb,
                       const unsigned short* __restrict__ z1b,
                       const float* __restrict__ alr,
                       unsigned short* __restrict__ dz1b,
                       unsigned short* __restrict__ dh2b) {
    size_t e = ((size_t)blockIdx.x * 256 + threadIdx.x) * 8;
    float a = alr[e >> 8] * (2.f / 256.f);
    union { unsigned short u[8]; uint4 v; } H, V, Z, DH, DZ;
    H.v = *(const uint4*)(h2b + e);
    V.v = *(const uint4*)(Vb + e);
    Z.v = *(const uint4*)(z1b + e);
#pragma unroll
    for (int j = 0; j < 8; j++) {
        float dh = a * (b2f(H.u[j]) - b2f(V.u[j]));
        float dz = dh * dsiluf(b2f(Z.u[j]));
        DH.u[j] = f2b(dh);
        DZ.u[j] = f2b(dz);
    }
    *(uint4*)(dh2b + e) = DH.v;
    *(uint4*)(dz1b + e) = DZ.v;
}

__global__ void colsum_k(const unsigned short* __restrict__ dz,
                         float* __restrict__ gb) {
    const int col = threadIdx.x;
    const size_t r0 = (size_t)blockIdx.x * 128;
    float s0 = 0, s1 = 0, s2 = 0, s3 = 0;
    for (int r = 0; r < 128; r += 4) {
        s0 += b2f(dz[(r0 + r) * 256 + col]);
        s1 += b2f(dz[(r0 + r + 1) * 256 + col]);
        s2 += b2f(dz[(r0 + r + 2) * 256 + col]);
        s3 += b2f(dz[(r0 + r + 3) * 256 + col]);
    }
    atomicAdd(&gb[col], s0 + s1 + s2 + s3);
}

__global__ void adamw_w_k(const float* __restrict__ Ws,
                          const float* __restrict__ accW,
                          unsigned short* __restrict__ nWt,
                          float* __restrict__ outSW) {
    int idx = blockIdx.x * 256 + threadIdx.x;  // 131072
    float g = accW[idx];
    outSW[idx] = -g;
    float nw = Ws[idx] * (1.f - LRc * WDc) - LRc * g / (fabsf(g) + EPSc);
    int l = idx >> 16, k = (idx >> 8) & 255, n = idx & 255;
    nWt[(size_t)l * 65536 + n * 256 + k] = f2b(nw);
}

__global__ void adamw_b_k(const float* __restrict__ bs,
                          const float* __restrict__ accB,
                          float* __restrict__ nb, float* __restrict__ outSb) {
    int idx = blockIdx.x * 256 + threadIdx.x;  // 512
    float g = accB[idx];
    outSb[idx] = -g;
    nb[idx] = bs[idx] * (1.f - LRc * WDc) - LRc * g / (fabsf(g) + EPSc);
}

__global__ void zero_k(float* p, int n) {
    int i = blockIdx.x * 256 + threadIdx.x;
    if (i < n) p[i] = 0.f;
}

extern "C" void kernel_launch(void* const* d_in, const int* in_sizes, int n_in,
                              void* d_out, int out_size, void* d_ws,
                              size_t ws_size, hipStream_t stream) {
    const float* x = (const float*)d_in[0];
    const float* Wk = (const float*)d_in[1];
    const float* Wq = (const float*)d_in[2];
    const float* Wv = (const float*)d_in[3];
    const float* Wlr = (const float*)d_in[4];
    const float* blr = (const float*)d_in[5];
    const float* Ws = (const float*)d_in[6];
    const float* bs = (const float*)d_in[7];

    unsigned short* S = (unsigned short*)d_ws;
    unsigned short* xb = S + 0 * NM;     // later: dz0T
    unsigned short* Kb = S + 1 * NM;     // later: r1b
    unsigned short* Qb = S + 2 * NM;
    unsigned short* Vb = S + 3 * NM;
    unsigned short* z0b = S + 4 * NM;
    unsigned short* h1b = S + 5 * NM;
    unsigned short* z1b = S + 6 * NM;    // later: dz0b
    unsigned short* h2b = S + 7 * NM;    // later: pbuf (with slot 8)
    unsigned short* dz1b = S + 8 * NM;
    unsigned short* dh2b = S + 9 * NM;
    unsigned short* KT = S + 10 * NM;
    unsigned short* h1T = S + 11 * NM;
    unsigned short* dz1T = S + 12 * NM;
    unsigned short* dz0T = xb;
    unsigned short* dz0b = z1b;
    unsigned short* r1b = Kb;
    float* pbuf = (float*)h2b;  // 2*64*65536 floats = slots 7+8

    unsigned short* wt = S + 13 * NM;
    unsigned short* Wkt = wt;
    unsigned short* W0t = wt + 3 * 65536;
    unsigned short* W1t = wt + 4 * 65536;
    unsigned short* W1b = wt + 5 * 65536;
    unsigned short* nW0t = wt + 6 * 65536;
    unsigned short* nW1t = wt + 7 * 65536;
    float* ft = (float*)(wt + 8 * 65536);
    float* alr = ft;                 // 32768
    float* accW = ft + 32768;        // 131072
    float* accB = accW + 131072;     // 512
    float* nb = accB + 512;          // 512

    float* out_ret = (float*)d_out;
    float* out_sW = out_ret + NM;
    float* out_sb = out_sW + 131072;

    dim3 blk(256);
    dim3 g_tall(2, 256);

    zero_k<<<2, blk, 0, stream>>>(accB, 512);
    cvtx_k<<<4096, blk, 0, stream>>>(x, xb);
    wprep_k<<<dim3(256, 6), blk, 0, stream>>>(Wk, Wq, Wv, Ws, wt);
    alr_k<<<8192, blk, 0, stream>>>(x, Wlr, blr, alr);

    // projections K,Q,V (batched over z)
    mgemm_k<0><<<dim3(2, 256, 3), blk, 0, stream>>>(
        xb, Wkt, nullptr, nullptr, nullptr, Kb, nullptr, nullptr, NM);

    // lmm forward
    mgemm_k<1><<<g_tall, blk, 0, stream>>>(Kb, W0t, bs, nullptr, nullptr, h1b,
                                           nullptr, z0b, 0);
    mgemm_k<1><<<g_tall, blk, 0, stream>>>(h1b, W1t, bs + 256, nullptr, nullptr,
                                           h2b, nullptr, z1b, 0);

    // backward elementwise + bias grads
    dzdh_k<<<4096, blk, 0, stream>>>(h2b, Vb, z1b, alr, dz1b, dh2b);
    colsum_k<<<256, blk, 0, stream>>>(dz1b, accB + 256);
    trans_k<<<dim3(512, 4, 3), blk, 0, stream>>>(Kb, h1b, dz1b, KT, h1T, dz1T);

    // dh1 = dz1@W1^T + dh2 ; dz0 = dh1 * dsilu(z0)  (fused)
    mgemm_k<2><<<g_tall, blk, 0, stream>>>(dz1b, W1b, nullptr, dh2b, z0b, dz0b,
                                           nullptr, nullptr, 0);
    colsum_k<<<256, blk, 0, stream>>>(dz0b, accB);
    trans_k<<<dim3(512, 4, 1), blk, 0, stream>>>(dz0b, dz0b, dz0b, dz0T, dz0T,
                                                 dz0T);

    // weight grads (split-K partials + reduce)
    rgemm_k<<<dim3(2, 2, 128), blk, 0, stream>>>(KT, h1T, dz0T, dz1T, pbuf);
    reduce_k<<<512, blk, 0, stream>>>(pbuf, accW);

    // AdamW + surprises
    adamw_w_k<<<512, blk, 0, stream>>>(Ws, accW, nW0t, out_sW);
    adamw_b_k<<<2, blk, 0, stream>>>(bs, accB, nb, out_sb);

    // retrieved with new weights
    mgemm_k<3><<<g_tall, blk, 0, stream>>>(Qb, nW0t, nb, nullptr, nullptr, r1b,
                                           nullptr, nullptr, 0);
    mgemm_k<4><<<g_tall, blk, 0, stream>>>(r1b, nW1t, nb + 256, nullptr, nullptr,
                                           nullptr, out_ret, nullptr, 0);
}

// Round 3
// 398.645 us; speedup vs baseline: 3.6815x; 1.0270x over previous
//
#include <hip/hip_runtime.h>
#include <math.h>

// NeuralMemory on MI355X — R3: register-direct MFMA GEMMs (no LDS, no barriers).
// Both mfma_f32_16x16x32_bf16 operand frags are 8 k-contiguous elems/lane, and
// all operands are stored k-contiguous, so frags load straight global->VGPR.
// Transposed copies (for the K=32768 reduction GEMMs) are written by the GEMM
// epilogues (C/D layout: each lane holds 4 consecutive rows of one column ->
// 8B-contiguous stores). dzdh elementwise fused into layer-1 fwd epilogue.

#define NTOK 32768
#define NM ((size_t)NTOK * 256)
#define LRc 1e-3f
#define WDc 1e-2f
#define EPSc 1e-8f

typedef __attribute__((ext_vector_type(8))) short bf16x8;
typedef __attribute__((ext_vector_type(4))) float f32x4;

__device__ __forceinline__ float b2f(unsigned short u) {
    union { unsigned int i; float f; } c;
    c.i = ((unsigned int)u) << 16;
    return c.f;
}
__device__ __forceinline__ unsigned short f2b(float f) {
    union { float f; unsigned int i; } c;
    c.f = f;
    unsigned int i = c.i;
    return (unsigned short)((i + 0x7FFFu + ((i >> 16) & 1u)) >> 16);
}
__device__ __forceinline__ float sigm(float z) { return 1.f / (1.f + __expf(-z)); }
__device__ __forceinline__ float siluf(float z) { return z * sigm(z); }
__device__ __forceinline__ float dsiluf(float z) {
    float s = sigm(z);
    return s * (1.f + z * (1.f - s));
}

// ---------------------------------------------------------------------------
// Tall MFMA GEMM, register-direct: C[M,256] = A[M,256] @ B, Bt[n][k]=B[k][n].
// Block 256 thr = 4 waves (2x2 of 64x64) covering 128x128; grid (2, M/128, z).
// EPI 0: Cb = A@B bf16 (batched z; z==0 also writes Tout)        projections
// EPI 1: z=acc+bias; Zout=z; Cb = A+silu(z); Tout                fwd layer 0
// EPI 5: z=acc+bias; h2=A+silu(z); dh=alr*(2/D)*(h2-V);          fwd layer 1
//        dz=dh*dsilu(z); Cb=dz; Rout=dh; Tout=dzT                 + bwd elem
// EPI 2: dh1=acc+Rin; dz0=dh1*dsilu(Zin); Cb=dz0; Tout           bwd layer 0
// EPI 3: Cb = A + silu(acc+bias)                                 retrieved L0
// EPI 4: Cf = A + silu(acc+bias)  (fp32)                         retrieved L1
// ---------------------------------------------------------------------------
template <int EPI>
__global__ __launch_bounds__(256, 2) void mgemm_k(
    const unsigned short* __restrict__ A, const unsigned short* __restrict__ Bt,
    const float* __restrict__ bias, const unsigned short* __restrict__ Rin,
    const unsigned short* __restrict__ Zin, const unsigned short* __restrict__ Vb,
    const float* __restrict__ alr, unsigned short* __restrict__ Cb,
    float* __restrict__ Cf, unsigned short* __restrict__ Zout,
    unsigned short* __restrict__ Rout, unsigned short* __restrict__ Tout,
    size_t zcs) {
    Bt += (size_t)blockIdx.z * 65536;
    Cb += (size_t)blockIdx.z * zcs;
    const int n0 = blockIdx.x * 128, m0 = blockIdx.y * 128;
    const int tid = threadIdx.x, lane = tid & 63, wave = tid >> 6;
    const int wr = (wave >> 1) * 64, wc = (wave & 1) * 64;
    const int fr = lane & 15, fk = (lane >> 4) * 8;

    const size_t base_a = (size_t)(m0 + wr + fr) * 256 + fk;
    const size_t base_b = (size_t)(n0 + wc + fr) * 256 + fk;

    f32x4 acc[4][4];
#pragma unroll
    for (int i = 0; i < 4; i++)
#pragma unroll
        for (int j = 0; j < 4; j++) acc[i][j] = (f32x4){0.f, 0.f, 0.f, 0.f};

#pragma unroll
    for (int k0 = 0; k0 < 256; k0 += 32) {
        bf16x8 af[4], bf[4];
#pragma unroll
        for (int i = 0; i < 4; i++) {
            af[i] = *(const bf16x8*)(A + base_a + (size_t)i * 4096 + k0);
            bf[i] = *(const bf16x8*)(Bt + base_b + (size_t)i * 4096 + k0);
        }
#pragma unroll
        for (int i = 0; i < 4; i++)
#pragma unroll
            for (int j = 0; j < 4; j++)
                acc[i][j] = __builtin_amdgcn_mfma_f32_16x16x32_bf16(
                    af[i], bf[j], acc[i][j], 0, 0, 0);
    }

    const int r0 = (lane >> 4) * 4, cc = lane & 15;
#pragma unroll
    for (int mi = 0; mi < 4; mi++) {
        const int grow0 = m0 + wr + mi * 16 + r0;
#pragma unroll
        for (int ni = 0; ni < 4; ni++) {
            const int gcol = n0 + wc + ni * 16 + cc;
            float bv = 0.f;
            if (EPI == 1 || EPI == 3 || EPI == 4 || EPI == 5) bv = bias[gcol];
            f32x4 c = acc[mi][ni];
            unsigned short tv[4];
            bool wt = false;
#pragma unroll
            for (int r = 0; r < 4; r++) {
                const size_t off = (size_t)(grow0 + r) * 256 + gcol;
                const float v = c[r];
                if (EPI == 0) {
                    unsigned short o = f2b(v);
                    Cb[off] = o;
                    tv[r] = o;
                    wt = (blockIdx.z == 0);
                } else if (EPI == 1) {
                    float z = v + bv;
                    Zout[off] = f2b(z);
                    unsigned short o = f2b(b2f(A[off]) + siluf(z));
                    Cb[off] = o;
                    tv[r] = o;
                    wt = true;
                } else if (EPI == 5) {
                    float z = v + bv;
                    float h2 = b2f(A[off]) + siluf(z);
                    float a = alr[grow0 + r] * (2.f / 256.f);
                    float dh = a * (h2 - b2f(Vb[off]));
                    float dz = dh * dsiluf(z);
                    unsigned short o = f2b(dz);
                    Cb[off] = o;
                    Rout[off] = f2b(dh);
                    tv[r] = o;
                    wt = true;
                } else if (EPI == 2) {
                    float dh1 = v + b2f(Rin[off]);
                    float dz0 = dh1 * dsiluf(b2f(Zin[off]));
                    unsigned short o = f2b(dz0);
                    Cb[off] = o;
                    tv[r] = o;
                    wt = true;
                } else if (EPI == 3) {
                    Cb[off] = f2b(b2f(A[off]) + siluf(v + bv));
                } else {
                    Cf[off] = b2f(A[off]) + siluf(v + bv);
                }
            }
            if (wt) {
                unsigned int w0 = (unsigned int)tv[0] | ((unsigned int)tv[1] << 16);
                unsigned int w1 = (unsigned int)tv[2] | ((unsigned int)tv[3] << 16);
                *(uint2*)&Tout[(size_t)gcol * 32768 + grow0] = make_uint2(w0, w1);
            }
        }
    }
}

// ---------------------------------------------------------------------------
// Reduction GEMM, register-direct: gW[l][i][j] = sum_t X[t][i] dz[t][j] via
// XT[i][t], dzT[j][t]. Split-K: blockIdx.z in [0,128): layer=z>>6, 512-token
// chunk. fp32 partials pbuf[layer][chunk][i][j]; reduce_k sums chunks.
// ---------------------------------------------------------------------------
__global__ __launch_bounds__(256, 2) void rgemm_k(
    const unsigned short* __restrict__ KT, const unsigned short* __restrict__ h1T,
    const unsigned short* __restrict__ dz0T,
    const unsigned short* __restrict__ dz1T, float* __restrict__ pbuf) {
    const int z = blockIdx.z, layer = z >> 6, zc = z & 63;
    const unsigned short* Ag = layer ? h1T : KT;
    const unsigned short* Bg = layer ? dz1T : dz0T;
    const int t0 = zc * 512;
    const int j0 = blockIdx.x * 128, i0 = blockIdx.y * 128;
    const int tid = threadIdx.x, lane = tid & 63, wave = tid >> 6;
    const int wr = (wave >> 1) * 64, wc = (wave & 1) * 64;
    const int fr = lane & 15, fk = (lane >> 4) * 8;

    const size_t base_a = (size_t)(i0 + wr + fr) * 32768 + fk;
    const size_t base_b = (size_t)(j0 + wc + fr) * 32768 + fk;

    f32x4 acc[4][4];
#pragma unroll
    for (int i = 0; i < 4; i++)
#pragma unroll
        for (int j = 0; j < 4; j++) acc[i][j] = (f32x4){0.f, 0.f, 0.f, 0.f};

#pragma unroll 4
    for (int tt = t0; tt < t0 + 512; tt += 32) {
        bf16x8 af[4], bf[4];
#pragma unroll
        for (int i = 0; i < 4; i++) {
            af[i] = *(const bf16x8*)(Ag + base_a + (size_t)i * 16 * 32768 + tt);
            bf[i] = *(const bf16x8*)(Bg + base_b + (size_t)i * 16 * 32768 + tt);
        }
#pragma unroll
        for (int i = 0; i < 4; i++)
#pragma unroll
            for (int j = 0; j < 4; j++)
                acc[i][j] = __builtin_amdgcn_mfma_f32_16x16x32_bf16(
                    af[i], bf[j], acc[i][j], 0, 0, 0);
    }

    float* P = pbuf + (size_t)(layer * 64 + zc) * 65536;
    const int r0 = (lane >> 4) * 4, cc = lane & 15;
#pragma unroll
    for (int mi = 0; mi < 4; mi++)
#pragma unroll
        for (int ni = 0; ni < 4; ni++) {
            f32x4 c = acc[mi][ni];
#pragma unroll
            for (int r = 0; r < 4; r++)
                P[(size_t)(i0 + wr + mi * 16 + r0 + r) * 256 +
                  (j0 + wc + ni * 16 + cc)] = c[r];
        }
}

__global__ void reduce_k(const float* __restrict__ pbuf, float* __restrict__ accW) {
    int idx = blockIdx.x * 256 + threadIdx.x;  // 131072
    int layer = idx >> 16, rc = idx & 65535;
    const float* p = pbuf + (size_t)layer * 64 * 65536 + rc;
    float s = 0.f;
#pragma unroll 8
    for (int c = 0; c < 64; c++) s += p[(size_t)c * 65536];
    accW[idx] = s;
}

__global__ void cvtx_k(const float* __restrict__ x, unsigned short* __restrict__ xb) {
    size_t i = ((size_t)blockIdx.x * 256 + threadIdx.x) * 8;
    float4 a = *(const float4*)(x + i);
    float4 b = *(const float4*)(x + i + 4);
    unsigned int w0 = (unsigned int)f2b(a.x) | ((unsigned int)f2b(a.y) << 16);
    unsigned int w1 = (unsigned int)f2b(a.z) | ((unsigned int)f2b(a.w) << 16);
    unsigned int w2 = (unsigned int)f2b(b.x) | ((unsigned int)f2b(b.y) << 16);
    unsigned int w3 = (unsigned int)f2b(b.z) | ((unsigned int)f2b(b.w) << 16);
    *(uint4*)(xb + i) = make_uint4(w0, w1, w2, w3);
}

// weight prep: z=0..4 transpose+cvt {Wk,Wq,Wv,Ws0,Ws1}; z=5 straight cvt Ws1
__global__ void wprep_k(const float* __restrict__ Wk, const float* __restrict__ Wq,
                        const float* __restrict__ Wv, const float* __restrict__ Ws,
                        unsigned short* __restrict__ wt) {
    const int z = blockIdx.y;
    const int idx = blockIdx.x * 256 + threadIdx.x;  // 0..65535
    const float* src = z == 0 ? Wk : z == 1 ? Wq : z == 2 ? Wv
                     : z == 3 ? Ws : Ws + 65536;
    unsigned short* dst = wt + (size_t)z * 65536;
    float v = src[idx];
    if (z == 5)
        dst[idx] = f2b(v);
    else
        dst[(idx & 255) * 256 + (idx >> 8)] = f2b(v);
}

__global__ __launch_bounds__(256) void alr_k(const float* __restrict__ x,
                                             const float* __restrict__ Wlr,
                                             const float* __restrict__ blr,
                                             float* __restrict__ alr) {
    const int wave = threadIdx.x >> 6, lane = threadIdx.x & 63;
    const int t = blockIdx.x * 4 + wave;
    const float* xr = x + (size_t)t * 256;
    float s = 0.f;
#pragma unroll
    for (int i = 0; i < 4; i++) s += xr[lane + i * 64] * Wlr[lane + i * 64];
#pragma unroll
    for (int off = 32; off; off >>= 1) s += __shfl_down(s, off);
    if (lane == 0) alr[t] = 0.1f * sigm(s + blr[0]);
}

__global__ void colsum_k(const unsigned short* __restrict__ dz,
                         float* __restrict__ gb) {
    const int col = threadIdx.x;
    const size_t r0 = (size_t)blockIdx.x * 128;
    float s0 = 0, s1 = 0, s2 = 0, s3 = 0;
    for (int r = 0; r < 128; r += 4) {
        s0 += b2f(dz[(r0 + r) * 256 + col]);
        s1 += b2f(dz[(r0 + r + 1) * 256 + col]);
        s2 += b2f(dz[(r0 + r + 2) * 256 + col]);
        s3 += b2f(dz[(r0 + r + 3) * 256 + col]);
    }
    atomicAdd(&gb[col], s0 + s1 + s2 + s3);
}

__global__ void adamw_w_k(const float* __restrict__ Ws,
                          const float* __restrict__ accW,
                          unsigned short* __restrict__ nWt,
                          float* __restrict__ outSW) {
    int idx = blockIdx.x * 256 + threadIdx.x;  // 131072
    float g = accW[idx];
    outSW[idx] = -g;
    float nw = Ws[idx] * (1.f - LRc * WDc) - LRc * g / (fabsf(g) + EPSc);
    int l = idx >> 16, k = (idx >> 8) & 255, n = idx & 255;
    nWt[(size_t)l * 65536 + n * 256 + k] = f2b(nw);
}

__global__ void adamw_b_k(const float* __restrict__ bs,
                          const float* __restrict__ accB,
                          float* __restrict__ nb, float* __restrict__ outSb) {
    int idx = blockIdx.x * 256 + threadIdx.x;  // 512
    float g = accB[idx];
    outSb[idx] = -g;
    nb[idx] = bs[idx] * (1.f - LRc * WDc) - LRc * g / (fabsf(g) + EPSc);
}

__global__ void zero_k(float* p, int n) {
    int i = blockIdx.x * 256 + threadIdx.x;
    if (i < n) p[i] = 0.f;
}

extern "C" void kernel_launch(void* const* d_in, const int* in_sizes, int n_in,
                              void* d_out, int out_size, void* d_ws,
                              size_t ws_size, hipStream_t stream) {
    const float* x = (const float*)d_in[0];
    const float* Wk = (const float*)d_in[1];
    const float* Wq = (const float*)d_in[2];
    const float* Wv = (const float*)d_in[3];
    const float* Wlr = (const float*)d_in[4];
    const float* blr = (const float*)d_in[5];
    const float* Ws = (const float*)d_in[6];
    const float* bs = (const float*)d_in[7];

    unsigned short* S = (unsigned short*)d_ws;
    unsigned short* xb = S + 0 * NM;
    unsigned short* z0b = S + 1 * NM;   // slots 1-2 reused as pbuf after death
    unsigned short* h1b = S + 2 * NM;
    unsigned short* Kb = S + 3 * NM;    // later r1b
    unsigned short* Qb = S + 4 * NM;
    unsigned short* Vb = S + 5 * NM;
    unsigned short* dz1b = S + 6 * NM;
    unsigned short* dh2b = S + 7 * NM;
    unsigned short* dz0b = S + 8 * NM;
    unsigned short* KT = S + 9 * NM;
    unsigned short* h1T = S + 10 * NM;
    unsigned short* dz1T = S + 11 * NM;
    unsigned short* dz0T = S + 12 * NM;
    float* pbuf = (float*)z0b;  // 32 MB, spans slots 1-2 (dead before rgemm)
    unsigned short* r1b = Kb;

    unsigned short* wt = S + 13 * NM;
    unsigned short* W0t = wt + 3 * 65536;
    unsigned short* W1t = wt + 4 * 65536;
    unsigned short* W1b = wt + 5 * 65536;
    unsigned short* nW0t = wt + 6 * 65536;
    unsigned short* nW1t = wt + 7 * 65536;
    float* ft = (float*)(wt + 8 * 65536);
    float* alr = ft;              // 32768
    float* accW = ft + 32768;     // 131072
    float* accB = accW + 131072;  // 512
    float* nb = accB + 512;       // 512

    float* out_ret = (float*)d_out;
    float* out_sW = out_ret + NM;
    float* out_sb = out_sW + 131072;

    dim3 blk(256);
    dim3 g_tall(2, 256);

    zero_k<<<2, blk, 0, stream>>>(accB, 512);
    cvtx_k<<<4096, blk, 0, stream>>>(x, xb);
    wprep_k<<<dim3(256, 6), blk, 0, stream>>>(Wk, Wq, Wv, Ws, wt);
    alr_k<<<8192, blk, 0, stream>>>(x, Wlr, blr, alr);

    // projections K,Q,V (batched over z); z==0 also writes KT
    mgemm_k<0><<<dim3(2, 256, 3), blk, 0, stream>>>(
        xb, wt, nullptr, nullptr, nullptr, nullptr, nullptr, Kb, nullptr,
        nullptr, nullptr, KT, NM);

    // fwd layer 0: h1 = K + silu(K@W0 + b0); saves z0, h1T
    mgemm_k<1><<<g_tall, blk, 0, stream>>>(Kb, W0t, bs, nullptr, nullptr,
                                           nullptr, nullptr, h1b, nullptr, z0b,
                                           nullptr, h1T, 0);

    // fwd layer 1 + bwd elementwise: dz1, dh2, dz1T (h2/z1 never materialized)
    mgemm_k<5><<<g_tall, blk, 0, stream>>>(h1b, W1t, bs + 256, nullptr, nullptr,
                                           Vb, alr, dz1b, nullptr, nullptr,
                                           dh2b, dz1T, 0);
    colsum_k<<<256, blk, 0, stream>>>(dz1b, accB + 256);

    // bwd layer 0: dz0 = (dz1@W1^T + dh2) * dsilu(z0); dz0T
    mgemm_k<2><<<g_tall, blk, 0, stream>>>(dz1b, W1b, nullptr, dh2b, z0b,
                                           nullptr, nullptr, dz0b, nullptr,
                                           nullptr, nullptr, dz0T, 0);
    colsum_k<<<256, blk, 0, stream>>>(dz0b, accB);

    // weight grads: split-K partials + reduce
    rgemm_k<<<dim3(2, 2, 128), blk, 0, stream>>>(KT, h1T, dz0T, dz1T, pbuf);
    reduce_k<<<512, blk, 0, stream>>>(pbuf, accW);

    // AdamW + surprises
    adamw_w_k<<<512, blk, 0, stream>>>(Ws, accW, nW0t, out_sW);
    adamw_b_k<<<2, blk, 0, stream>>>(bs, accB, nb, out_sb);

    // retrieved with new weights
    mgemm_k<3><<<g_tall, blk, 0, stream>>>(Qb, nW0t, nb, nullptr, nullptr,
                                           nullptr, nullptr, r1b, nullptr,
                                           nullptr, nullptr, nullptr, 0);
    mgemm_k<4><<<g_tall, blk, 0, stream>>>(r1b, nW1t, nb + 256, nullptr,
                                           nullptr, nullptr, nullptr, nullptr,
                                           out_ret, nullptr, nullptr, nullptr,
                                           0);
}

// Round 4
// 382.360 us; speedup vs baseline: 3.8383x; 1.0426x over previous
//
#include <hip/hip_runtime.h>
#include <math.h>

// NeuralMemory on MI355X — R4: occupancy (launch_bounds 256,4 => <=128 unified
// regs => 16 waves/CU) + traffic fusion: no transposed copies (rgemm does
// LDS transpose-on-load), colsum fused into GEMM epilogues, alr fused into
// x-convert, retrieved L0+L1 fused via 64KB LDS round-trip, pbuf 16MB.

#define NTOK 32768
#define NM ((size_t)NTOK * 256)
#define LRc 1e-3f
#define WDc 1e-2f
#define EPSc 1e-8f

typedef __attribute__((ext_vector_type(8))) short bf16x8;
typedef __attribute__((ext_vector_type(4))) float f32x4;

__device__ __forceinline__ float b2f(unsigned short u) {
    union { unsigned int i; float f; } c;
    c.i = ((unsigned int)u) << 16;
    return c.f;
}
__device__ __forceinline__ unsigned short f2b(float f) {
    union { float f; unsigned int i; } c;
    c.f = f;
    unsigned int i = c.i;
    return (unsigned short)((i + 0x7FFFu + ((i >> 16) & 1u)) >> 16);
}
__device__ __forceinline__ float sigm(float z) { return 1.f / (1.f + __expf(-z)); }
__device__ __forceinline__ float siluf(float z) { return z * sigm(z); }
__device__ __forceinline__ float dsiluf(float z) {
    float s = sigm(z);
    return s * (1.f + z * (1.f - s));
}

// ---------------------------------------------------------------------------
// Tall MFMA GEMM, register-direct (no LDS): C[M,256] = A @ B, Bt[n][k]=B[k][n].
// 4 waves (2x2 of 64x64) per block over a 128x128 tile; grid (2, 256[, z]).
// EPI 0: Cb = A@B (batched z)                                  projections
// EPI 1: z=acc+bias; Zout=z; Cb = A+silu(z)                    fwd layer 0
// EPI 5: z=acc+bias; h2=A+silu(z); dh=alr*(2/D)*(h2-V);        fwd layer 1 +
//        dz=dh*dsilu(z); Cb=dz; Rout=dh; gb += colsum(dz)       bwd elemwise
// EPI 2: dh1=acc+Rin; dz0=dh1*dsilu(Zin); Cb=dz0; gb+=colsum   bwd layer 0
// ---------------------------------------------------------------------------
template <int EPI>
__global__ __launch_bounds__(256, 4) void mgemm_k(
    const unsigned short* __restrict__ A, const unsigned short* __restrict__ Bt,
    const float* __restrict__ bias, const unsigned short* __restrict__ Rin,
    const unsigned short* __restrict__ Zin, const unsigned short* __restrict__ Vb,
    const float* __restrict__ alr, unsigned short* __restrict__ Cb,
    unsigned short* __restrict__ Zout, unsigned short* __restrict__ Rout,
    float* __restrict__ gb, size_t zcs) {
    Bt += (size_t)blockIdx.z * 65536;
    Cb += (size_t)blockIdx.z * zcs;
    const int n0 = blockIdx.x * 128, m0 = blockIdx.y * 128;
    const int tid = threadIdx.x, lane = tid & 63, wave = tid >> 6;
    const int wr = (wave >> 1) * 64, wc = (wave & 1) * 64;
    const int fr = lane & 15, fk = (lane >> 4) * 8;

    const size_t base_a = (size_t)(m0 + wr + fr) * 256 + fk;
    const size_t base_b = (size_t)(n0 + wc + fr) * 256 + fk;

    f32x4 acc[4][4];
#pragma unroll
    for (int i = 0; i < 4; i++)
#pragma unroll
        for (int j = 0; j < 4; j++) acc[i][j] = (f32x4){0.f, 0.f, 0.f, 0.f};

#pragma unroll
    for (int k0 = 0; k0 < 256; k0 += 32) {
        bf16x8 af[4], bf[4];
#pragma unroll
        for (int i = 0; i < 4; i++) {
            af[i] = *(const bf16x8*)(A + base_a + (size_t)i * 4096 + k0);
            bf[i] = *(const bf16x8*)(Bt + base_b + (size_t)i * 4096 + k0);
        }
#pragma unroll
        for (int i = 0; i < 4; i++)
#pragma unroll
            for (int j = 0; j < 4; j++)
                acc[i][j] = __builtin_amdgcn_mfma_f32_16x16x32_bf16(
                    af[i], bf[j], acc[i][j], 0, 0, 0);
    }

    const int r0 = (lane >> 4) * 4, cc = lane & 15;
    float csum[4] = {0.f, 0.f, 0.f, 0.f};
#pragma unroll
    for (int mi = 0; mi < 4; mi++) {
        const int grow0 = m0 + wr + mi * 16 + r0;
#pragma unroll
        for (int ni = 0; ni < 4; ni++) {
            const int gcol = n0 + wc + ni * 16 + cc;
            float bv = 0.f;
            if (EPI == 1 || EPI == 5) bv = bias[gcol];
            f32x4 c = acc[mi][ni];
#pragma unroll
            for (int r = 0; r < 4; r++) {
                const size_t off = (size_t)(grow0 + r) * 256 + gcol;
                const float v = c[r];
                if (EPI == 0) {
                    Cb[off] = f2b(v);
                } else if (EPI == 1) {
                    float z = v + bv;
                    Zout[off] = f2b(z);
                    Cb[off] = f2b(b2f(A[off]) + siluf(z));
                } else if (EPI == 5) {
                    float z = v + bv;
                    float h2 = b2f(A[off]) + siluf(z);
                    float a = alr[grow0 + r] * (2.f / 256.f);
                    float dh = a * (h2 - b2f(Vb[off]));
                    float dz = dh * dsiluf(z);
                    Cb[off] = f2b(dz);
                    Rout[off] = f2b(dh);
                    csum[ni] += dz;
                } else if (EPI == 2) {
                    float dh1 = v + b2f(Rin[off]);
                    float dz0 = dh1 * dsiluf(b2f(Zin[off]));
                    Cb[off] = f2b(dz0);
                    csum[ni] += dz0;
                }
            }
        }
    }
    if (EPI == 5 || EPI == 2) {
#pragma unroll
        for (int ni = 0; ni < 4; ni++) {
            float v = csum[ni];
            v += __shfl_down(v, 32);
            v += __shfl_down(v, 16);
            if (lane < 16) atomicAdd(&gb[n0 + wc + ni * 16 + cc], v);
        }
    }
}

// ---------------------------------------------------------------------------
// Reduction GEMM with transpose-on-load: gW[l][i][j] = sum_t X[t][i] dz[t][j]
// from ROW-MAJOR X, dz. Grid (2,2,64): j0, i0, z (layer = z>>5, chunk = z&31,
// 1024 tokens). LDS tiles As[i][t], Bs[j][t] (128x32 shorts) with octet XOR
// swizzle to spread banks. fp32 partials pbuf[layer][chunk][i][j].
// ---------------------------------------------------------------------------
__device__ __forceinline__ int taddr(int i, int t) {
    return i * 32 + ((((t >> 3) ^ (i >> 3)) & 3) * 8) + (t & 7);
}

__global__ __launch_bounds__(256, 4) void rgemm_k(
    const unsigned short* __restrict__ Kb, const unsigned short* __restrict__ h1b,
    const unsigned short* __restrict__ dz0b,
    const unsigned short* __restrict__ dz1b, float* __restrict__ pbuf) {
    __shared__ unsigned short As[128 * 32];
    __shared__ unsigned short Bs[128 * 32];
    const int z = blockIdx.z, layer = z >> 5, zc = z & 31;
    const unsigned short* Ag = layer ? h1b : Kb;
    const unsigned short* Bg = layer ? dz1b : dz0b;
    const int t0 = zc * 1024;
    const int j0 = blockIdx.x * 128, i0 = blockIdx.y * 128;
    const int tid = threadIdx.x, lane = tid & 63, wave = tid >> 6;
    const int wr = (wave >> 1) * 64, wc = (wave & 1) * 64;
    const int fr = lane & 15, fk = (lane >> 4) * 8;
    const int pt = (tid >> 4) * 2, pi = (tid & 15) * 8;

    f32x4 acc[4][4];
#pragma unroll
    for (int i = 0; i < 4; i++)
#pragma unroll
        for (int j = 0; j < 4; j++) acc[i][j] = (f32x4){0.f, 0.f, 0.f, 0.f};

    for (int tt = t0; tt < t0 + 1024; tt += 32) {
        // stage transposed tiles
        uint4 a0 = *(const uint4*)(Ag + (size_t)(tt + pt) * 256 + i0 + pi);
        uint4 a1 = *(const uint4*)(Ag + (size_t)(tt + pt + 1) * 256 + i0 + pi);
        uint4 b0 = *(const uint4*)(Bg + (size_t)(tt + pt) * 256 + j0 + pi);
        uint4 b1 = *(const uint4*)(Bg + (size_t)(tt + pt + 1) * 256 + j0 + pi);
        const unsigned int* aw0 = (const unsigned int*)&a0;
        const unsigned int* aw1 = (const unsigned int*)&a1;
        const unsigned int* bw0 = (const unsigned int*)&b0;
        const unsigned int* bw1 = (const unsigned int*)&b1;
#pragma unroll
        for (int ii = 0; ii < 8; ii++) {
            unsigned int alo = (aw0[ii >> 1] >> (16 * (ii & 1))) & 0xFFFFu;
            unsigned int ahi = (aw1[ii >> 1] >> (16 * (ii & 1))) & 0xFFFFu;
            unsigned int blo = (bw0[ii >> 1] >> (16 * (ii & 1))) & 0xFFFFu;
            unsigned int bhi = (bw1[ii >> 1] >> (16 * (ii & 1))) & 0xFFFFu;
            ((unsigned int*)As)[taddr(pi + ii, pt) >> 1] = alo | (ahi << 16);
            ((unsigned int*)Bs)[taddr(pi + ii, pt) >> 1] = blo | (bhi << 16);
        }
        __syncthreads();
        bf16x8 af[4], bf[4];
#pragma unroll
        for (int i = 0; i < 4; i++) {
            af[i] = *(const bf16x8*)&As[taddr(wr + i * 16 + fr, fk)];
            bf[i] = *(const bf16x8*)&Bs[taddr(wc + i * 16 + fr, fk)];
        }
#pragma unroll
        for (int i = 0; i < 4; i++)
#pragma unroll
            for (int j = 0; j < 4; j++)
                acc[i][j] = __builtin_amdgcn_mfma_f32_16x16x32_bf16(
                    af[i], bf[j], acc[i][j], 0, 0, 0);
        __syncthreads();
    }

    float* P = pbuf + (size_t)((layer << 5) + zc) * 65536;
    const int r0 = (lane >> 4) * 4, cc = lane & 15;
#pragma unroll
    for (int mi = 0; mi < 4; mi++)
#pragma unroll
        for (int ni = 0; ni < 4; ni++) {
            f32x4 c = acc[mi][ni];
#pragma unroll
            for (int r = 0; r < 4; r++)
                P[(size_t)(i0 + wr + mi * 16 + r0 + r) * 256 +
                  (j0 + wc + ni * 16 + cc)] = c[r];
        }
}

__global__ void reduce_k(const float* __restrict__ pbuf, float* __restrict__ accW) {
    int idx = blockIdx.x * 256 + threadIdx.x;  // 131072
    int layer = idx >> 16, rc = idx & 65535;
    const float* p = pbuf + (size_t)layer * 32 * 65536 + rc;
    float s = 0.f;
#pragma unroll 8
    for (int c = 0; c < 32; c++) s += p[(size_t)c * 65536];
    accW[idx] = s;
}

// ---------------------------------------------------------------------------
// Fused retrieved: r1 = Q + silu(Q@W0'+b0') (kept in 64KB LDS), then
// out = r1 + silu(r1@W1'+b1') in fp32. One block per 128 rows.
// ---------------------------------------------------------------------------
__global__ __launch_bounds__(256, 2) void retr_k(
    const unsigned short* __restrict__ Qb, const unsigned short* __restrict__ W0t,
    const unsigned short* __restrict__ W1t, const float* __restrict__ nb,
    float* __restrict__ out) {
    __shared__ unsigned short Ls[128 * 256];
    const int m0 = blockIdx.x * 128;
    const int tid = threadIdx.x, lane = tid & 63, wave = tid >> 6;
    const int wr = (wave >> 1) * 64, wc = (wave & 1) * 64;
    const int fr = lane & 15, fk = (lane >> 4) * 8;
    const int r0 = (lane >> 4) * 4, cc = lane & 15;

    // phase 1: r1 tile -> LDS
#pragma unroll
    for (int nh = 0; nh < 2; nh++) {
        f32x4 acc[4][4];
#pragma unroll
        for (int i = 0; i < 4; i++)
#pragma unroll
            for (int j = 0; j < 4; j++) acc[i][j] = (f32x4){0.f, 0.f, 0.f, 0.f};
        const size_t base_a = (size_t)(m0 + wr + fr) * 256 + fk;
        const size_t base_b = (size_t)(nh * 128 + wc + fr) * 256 + fk;
#pragma unroll
        for (int k0 = 0; k0 < 256; k0 += 32) {
            bf16x8 af[4], bf[4];
#pragma unroll
            for (int i = 0; i < 4; i++) {
                af[i] = *(const bf16x8*)(Qb + base_a + (size_t)i * 4096 + k0);
                bf[i] = *(const bf16x8*)(W0t + base_b + (size_t)i * 4096 + k0);
            }
#pragma unroll
            for (int i = 0; i < 4; i++)
#pragma unroll
                for (int j = 0; j < 4; j++)
                    acc[i][j] = __builtin_amdgcn_mfma_f32_16x16x32_bf16(
                        af[i], bf[j], acc[i][j], 0, 0, 0);
        }
#pragma unroll
        for (int mi = 0; mi < 4; mi++)
#pragma unroll
            for (int ni = 0; ni < 4; ni++) {
                const int ncol = nh * 128 + wc + ni * 16 + cc;
                const float bv = nb[ncol];
                f32x4 c = acc[mi][ni];
#pragma unroll
                for (int r = 0; r < 4; r++) {
                    const int rowl = wr + mi * 16 + r0 + r;
                    const size_t off = (size_t)(m0 + rowl) * 256 + ncol;
                    Ls[rowl * 256 + ncol] = f2b(b2f(Qb[off]) + siluf(c[r] + bv));
                }
            }
    }
    __syncthreads();

    // phase 2: out = r1 + silu(r1 @ W1' + b1')
#pragma unroll
    for (int nh = 0; nh < 2; nh++) {
        f32x4 acc[4][4];
#pragma unroll
        for (int i = 0; i < 4; i++)
#pragma unroll
            for (int j = 0; j < 4; j++) acc[i][j] = (f32x4){0.f, 0.f, 0.f, 0.f};
        const size_t base_b = (size_t)(nh * 128 + wc + fr) * 256 + fk;
#pragma unroll
        for (int k0 = 0; k0 < 256; k0 += 32) {
            bf16x8 af[4], bf[4];
#pragma unroll
            for (int i = 0; i < 4; i++) {
                af[i] = *(const bf16x8*)&Ls[(wr + i * 16 + fr) * 256 + k0 + fk];
                bf[i] = *(const bf16x8*)(W1t + base_b + (size_t)i * 4096 + k0);
            }
#pragma unroll
            for (int i = 0; i < 4; i++)
#pragma unroll
                for (int j = 0; j < 4; j++)
                    acc[i][j] = __builtin_amdgcn_mfma_f32_16x16x32_bf16(
                        af[i], bf[j], acc[i][j], 0, 0, 0);
        }
#pragma unroll
        for (int mi = 0; mi < 4; mi++)
#pragma unroll
            for (int ni = 0; ni < 4; ni++) {
                const int ncol = nh * 128 + wc + ni * 16 + cc;
                const float bv = nb[256 + ncol];
                f32x4 c = acc[mi][ni];
#pragma unroll
                for (int r = 0; r < 4; r++) {
                    const int rowl = wr + mi * 16 + r0 + r;
                    float r1v = b2f(Ls[rowl * 256 + ncol]);
                    out[(size_t)(m0 + rowl) * 256 + ncol] =
                        r1v + siluf(c[r] + bv);
                }
            }
    }
}

// x fp32 -> xb bf16 + alr = 0.1*sigmoid(x@Wlr+blr), one wave per row
__global__ __launch_bounds__(256) void prep_k(const float* __restrict__ x,
                                              const float* __restrict__ Wlr,
                                              const float* __restrict__ blr,
                                              unsigned short* __restrict__ xb,
                                              float* __restrict__ alr) {
    const int wave = threadIdx.x >> 6, lane = threadIdx.x & 63;
    const int r = blockIdx.x * 4 + wave;
    float4 w = *(const float4*)(Wlr + lane * 4);
    float4 v = *(const float4*)(x + (size_t)r * 256 + lane * 4);
    float s = v.x * w.x + v.y * w.y + v.z * w.z + v.w * w.w;
    unsigned int p0 = (unsigned int)f2b(v.x) | ((unsigned int)f2b(v.y) << 16);
    unsigned int p1 = (unsigned int)f2b(v.z) | ((unsigned int)f2b(v.w) << 16);
    *(uint2*)(xb + (size_t)r * 256 + lane * 4) = make_uint2(p0, p1);
#pragma unroll
    for (int off = 32; off; off >>= 1) s += __shfl_down(s, off);
    if (lane == 0) alr[r] = 0.1f * sigm(s + blr[0]);
}

// weight prep: z=0..4 transpose+cvt {Wk,Wq,Wv,Ws0,Ws1}; z=5 straight cvt Ws1
__global__ void wprep_k(const float* __restrict__ Wk, const float* __restrict__ Wq,
                        const float* __restrict__ Wv, const float* __restrict__ Ws,
                        unsigned short* __restrict__ wt) {
    const int z = blockIdx.y;
    const int idx = blockIdx.x * 256 + threadIdx.x;  // 0..65535
    const float* src = z == 0 ? Wk : z == 1 ? Wq : z == 2 ? Wv
                     : z == 3 ? Ws : Ws + 65536;
    unsigned short* dst = wt + (size_t)z * 65536;
    float v = src[idx];
    if (z == 5)
        dst[idx] = f2b(v);
    else
        dst[(idx & 255) * 256 + (idx >> 8)] = f2b(v);
}

__global__ void adamw_w_k(const float* __restrict__ Ws,
                          const float* __restrict__ accW,
                          unsigned short* __restrict__ nWt,
                          float* __restrict__ outSW) {
    int idx = blockIdx.x * 256 + threadIdx.x;  // 131072
    float g = accW[idx];
    outSW[idx] = -g;
    float nw = Ws[idx] * (1.f - LRc * WDc) - LRc * g / (fabsf(g) + EPSc);
    int l = idx >> 16, k = (idx >> 8) & 255, n = idx & 255;
    nWt[(size_t)l * 65536 + n * 256 + k] = f2b(nw);
}

__global__ void adamw_b_k(const float* __restrict__ bs,
                          const float* __restrict__ accB,
                          float* __restrict__ nb, float* __restrict__ outSb) {
    int idx = blockIdx.x * 256 + threadIdx.x;  // 512
    float g = accB[idx];
    outSb[idx] = -g;
    nb[idx] = bs[idx] * (1.f - LRc * WDc) - LRc * g / (fabsf(g) + EPSc);
}

__global__ void zero_k(float* p, int n) {
    int i = blockIdx.x * 256 + threadIdx.x;
    if (i < n) p[i] = 0.f;
}

extern "C" void kernel_launch(void* const* d_in, const int* in_sizes, int n_in,
                              void* d_out, int out_size, void* d_ws,
                              size_t ws_size, hipStream_t stream) {
    const float* x = (const float*)d_in[0];
    const float* Wk = (const float*)d_in[1];
    const float* Wq = (const float*)d_in[2];
    const float* Wv = (const float*)d_in[3];
    const float* Wlr = (const float*)d_in[4];
    const float* blr = (const float*)d_in[5];
    const float* Ws = (const float*)d_in[6];
    const float* bs = (const float*)d_in[7];

    unsigned short* S = (unsigned short*)d_ws;
    unsigned short* xb = S + 0 * NM;
    unsigned short* Kb = S + 1 * NM;
    unsigned short* Qb = S + 2 * NM;
    unsigned short* Vb = S + 3 * NM;
    unsigned short* z0b = S + 4 * NM;
    unsigned short* h1b = S + 5 * NM;
    unsigned short* dz1b = S + 6 * NM;
    unsigned short* dh2b = S + 7 * NM;
    unsigned short* dz0b = S + 8 * NM;
    float* pbuf = (float*)(S + 9 * NM);  // 16 MB (2 layers x 32 chunks x 64K)

    unsigned short* wt = S + 11 * NM;
    unsigned short* W0t = wt + 3 * 65536;
    unsigned short* W1t = wt + 4 * 65536;
    unsigned short* W1b = wt + 5 * 65536;
    unsigned short* nW0t = wt + 6 * 65536;
    unsigned short* nW1t = wt + 7 * 65536;
    float* ft = (float*)(wt + 8 * 65536);
    float* alr = ft;              // 32768
    float* accW = ft + 32768;     // 131072
    float* accB = accW + 131072;  // 512
    float* nb = accB + 512;       // 512

    float* out_ret = (float*)d_out;
    float* out_sW = out_ret + NM;
    float* out_sb = out_sW + 131072;

    dim3 blk(256);
    dim3 g_tall(2, 256);

    zero_k<<<2, blk, 0, stream>>>(accB, 512);
    prep_k<<<8192, blk, 0, stream>>>(x, Wlr, blr, xb, alr);
    wprep_k<<<dim3(256, 6), blk, 0, stream>>>(Wk, Wq, Wv, Ws, wt);

    // projections K,Q,V (batched over z)
    mgemm_k<0><<<dim3(2, 256, 3), blk, 0, stream>>>(
        xb, wt, nullptr, nullptr, nullptr, nullptr, nullptr, Kb, nullptr,
        nullptr, nullptr, NM);

    // fwd layer 0: h1 = K + silu(K@W0 + b0); saves z0
    mgemm_k<1><<<g_tall, blk, 0, stream>>>(Kb, W0t, bs, nullptr, nullptr,
                                           nullptr, nullptr, h1b, z0b, nullptr,
                                           nullptr, 0);

    // fwd layer 1 + bwd elementwise (+ gb1 colsum fused)
    mgemm_k<5><<<g_tall, blk, 0, stream>>>(h1b, W1t, bs + 256, nullptr, nullptr,
                                           Vb, alr, dz1b, nullptr, dh2b,
                                           accB + 256, 0);

    // bwd layer 0: dz0 = (dz1@W1^T + dh2) * dsilu(z0) (+ gb0 colsum fused)
    mgemm_k<2><<<g_tall, blk, 0, stream>>>(dz1b, W1b, nullptr, dh2b, z0b,
                                           nullptr, nullptr, dz0b, nullptr,
                                           nullptr, accB, 0);

    // weight grads: transpose-on-load split-K partials + reduce
    rgemm_k<<<dim3(2, 2, 64), blk, 0, stream>>>(Kb, h1b, dz0b, dz1b, pbuf);
    reduce_k<<<512, blk, 0, stream>>>(pbuf, accW);

    // AdamW + surprises
    adamw_w_k<<<512, blk, 0, stream>>>(Ws, accW, nW0t, out_sW);
    adamw_b_k<<<2, blk, 0, stream>>>(bs, accB, nb, out_sb);

    // retrieved (both layers fused via LDS)
    retr_k<<<256, blk, 0, stream>>>(Qb, nW0t, nW1t, nb, out_ret);
}